// Round 5
// baseline (287.060 us; speedup 1.0000x reference)
//
#include <hip/hip_runtime.h>

// SNN forward, round 5.
// convP = round-3 convM + explicit register pipelining:
//   - B-fragments prefetched one TAP ahead (8 ds_read issued ~256 cyc before use)
//   - A-fragments prefetched one (tap,cq) ahead
//   - wfrag replicated 4x (blocks use copy (bx+by)&3) to kill L2 same-line contention
//   - MSTR back to 136 (round-4's 144 caused 2-way bank conflicts)
// Accumulation order identical to rounds 3/4 -> bit-identical u.

typedef __attribute__((ext_vector_type(8))) _Float16 v8h;
typedef __attribute__((ext_vector_type(16))) float v16f;
typedef _Float16 half_t;

#define NB 32
#define NC 64
#define NT 129
#define TIN 128
#define NM 40
#define MSTR 136          // LDS per-slot stride: conflict-free (verified round 3: 0 conflicts)
#define SROWB 5120        // global spike row bytes = 40*64*2

// ---- weights -> MFMA A-fragments, 4 replicated copies ----
// copy c at wf + c*12288; order [tap12][cq4][ct2][hl2][lane64] x 16B
__global__ void prep_wfrag(const float* __restrict__ w, uint4* __restrict__ wf) {
    int tid = blockIdx.x * 256 + threadIdx.x;   // 12288
    if (tid >= 12288) return;
    int lane = tid & 63;
    int rest = tid >> 6;
    int hl = rest & 1;
    int ct = (rest >> 1) & 1;
    int cq = (rest >> 2) & 3;
    int tap = rest >> 4;
    int kh = tap / 3, kw = tap % 3;
    int co = ct * 32 + (lane & 31);
    unsigned short o[8];
#pragma unroll
    for (int jj = 0; jj < 8; jj++) {
        int ci = cq * 16 + (lane >> 5) * 8 + jj;
        float wv = w[((co * 64 + ci) * 4 + kh) * 3 + kw];
        _Float16 hi = (_Float16)wv;
        _Float16 val = hl ? (_Float16)((wv - (float)hi) * 2048.0f) : hi;
        unsigned short us;
        __builtin_memcpy(&us, &val, 2);
        o[jj] = us;
    }
    uint4 r;
    __builtin_memcpy(&r, o, 16);
#pragma unroll
    for (int c = 0; c < 4; c++) wf[c * 12288 + tid] = r;
}

// ---- conv1 (1->64ch, 4x3, pad(2,1)) + LIF1, unroll-8 row prefetch ----
__global__ void conv1_lif1(const float* __restrict__ x, const float* __restrict__ w1,
                           half_t* __restrict__ s1) {
    const int mg = blockIdx.x;        // 0..9
    const int b = blockIdx.y;
    const int c = threadIdx.x & 63;
    const int ml = threadIdx.x >> 6;  // 0..3
    const int m = mg * 4 + ml;
    float w[4][3];
#pragma unroll
    for (int kh = 0; kh < 4; kh++)
#pragma unroll
        for (int kw = 0; kw < 3; kw++) w[kh][kw] = w1[(c * 4 + kh) * 3 + kw];
    const float* xb = x + (size_t)b * TIN * NM;

    float xw[12][3];                  // rows tb-2 .. tb+9
#pragma unroll
    for (int rr = 0; rr < 12; rr++)
#pragma unroll
        for (int kw = 0; kw < 3; kw++) xw[rr][kw] = 0.f;
#pragma unroll
    for (int rr = 2; rr < 4; rr++)
#pragma unroll
        for (int kw = 0; kw < 3; kw++) {
            int mc = m - 1 + kw;
            xw[rr][kw] = ((unsigned)mc < (unsigned)NM) ? xb[(rr - 2) * NM + mc] : 0.f;
        }

    half_t* orow = s1 + ((size_t)b * NT * NM + m) * 64 + c;
    float v = 0.f;
    const float TAUc = 10.0f / 7.0f;

    for (int tb = 0; tb < NT; tb += 8) {
#pragma unroll
        for (int q = 0; q < 8; q++) {
            int row = tb + 2 + q;
#pragma unroll
            for (int kw = 0; kw < 3; kw++) {
                int mc = m - 1 + kw;
                xw[4 + q][kw] = (row < TIN && (unsigned)mc < (unsigned)NM)
                                    ? xb[row * NM + mc] : 0.f;
            }
        }
        int kmax = (NT - tb) < 8 ? (NT - tb) : 8;
#pragma unroll
        for (int k = 0; k < 8; k++) {
            if (k < kmax) {
                float uacc = 0.f;
#pragma unroll
                for (int kh = 0; kh < 4; kh++)
#pragma unroll
                    for (int kw = 0; kw < 3; kw++) uacc += xw[k + kh][kw] * w[kh][kw];
                v = v + (uacc - v) / TAUc;
                float s = (v >= 1.0f) ? 1.0f : 0.0f;
                orow[(size_t)(tb + k) * NM * 64] = (half_t)s;
                if (v >= 1.0f) v = 0.0f;
            }
        }
#pragma unroll
        for (int rr = 0; rr < 4; rr++)
#pragma unroll
            for (int kw = 0; kw < 3; kw++) xw[rr][kw] = xw[8 + rr][kw];
    }
}

// ---- MFMA conv 64->64, 4x3 dilated; explicit register pipeline ----
// grid (33,B). 256 thr = 4 waves x 2 pos-tiles (2j x 16m). One barrier.
template <int DH, int PH, int DW, int PW, int EXT, int RSH>
__global__ __launch_bounds__(256, 2) void convP(const half_t* __restrict__ spk,
                                                const uint4* __restrict__ wfrag,
                                                float* __restrict__ u) {
    extern __shared__ char lds[];
    constexpr int LROWB = EXT * MSTR;
    constexpr int NCH = 7 * EXT * 8;
    const int tid = threadIdx.x;
    const int lane = tid & 63;
    const int wv = tid >> 6;                    // 0..3
    const int bx = blockIdx.x;                  // 0..32
    const int b = blockIdx.y;
    int r, q;
    if (bx < 32) { r = bx & ((1 << RSH) - 1); q = bx >> RSH; }
    else         { r = 0; q = 32 >> RSH; }
    const int j0 = 4 * q;

    // ---- stage 7 lattice rows (zero-fill OOB), one barrier ----
    const char* spb = (const char*)spk + (size_t)b * NT * SROWB;
#pragma unroll
    for (int k = 0; k < (NCH + 255) / 256; k++) {
        int c = tid + k * 256;
        if (c < NCH) {
            int i = c / (EXT * 8);
            int rem = c - i * (EXT * 8);
            int s = rem >> 3;
            int ci8 = rem & 7;
            int tg = r - PH + DH * (j0 + i);
            int md = s - PW;
            uint4 val = make_uint4(0u, 0u, 0u, 0u);
            if ((unsigned)tg < (unsigned)NT && (unsigned)md < (unsigned)NM)
                val = *(const uint4*)(spb + ((size_t)tg * NM + md) * 128 + ci8 * 16);
            *(uint4*)(lds + i * LROWB + s * MSTR + ci8 * 16) = val;
        }
    }
    __syncthreads();

    // ---- lane decode: 6 real pos-tiles on 8 slots (tau 6,7 dummy) ----
    const int pos = lane & 31;
    const int jlocal = pos >> 4;
    const int mloc = pos & 15;
    const int hseg = lane >> 5;

    int baseB[2], mm[2], tt[2];
    bool tvalid[2];
#pragma unroll
    for (int pt = 0; pt < 2; pt++) {
        int tau = 2 * wv + pt;
        tvalid[pt] = (tau <= 5);
        int tauc = tvalid[pt] ? tau : 5;
        int jp = tauc / 3;
        int mc = tauc - 3 * jp;
        int j = 2 * jp + jlocal;                // 0..3
        int m = mc * 16 + mloc;                 // 0..47
        int meff = m > 39 ? 39 : m;
        mm[pt] = m;
        tt[pt] = r + DH * (j0 + j);
        baseB[pt] = j * LROWB + meff * MSTR + hseg * 16;
    }

    v16f acc[2][2][2];                          // [pos-tile][co-tile][hi/lo]
#pragma unroll
    for (int a = 0; a < 2; a++)
#pragma unroll
        for (int c = 0; c < 2; c++)
#pragma unroll
            for (int h = 0; h < 2; h++) acc[a][c][h] = (v16f)(0.0f);

    // wfrag copy selection: decorrelate L2 lines across blocks
    const uint4* wp = wfrag + ((size_t)((bx + b) & 3)) * 12288 + lane;

    // ---- pipelined K-loop: B prefetch one TAP ahead, A one (tap,cq) ahead ----
    v8h Bbuf[2][2][4];                          // [buf][pt][cq]
    v8h Abuf[2][4];                             // [buf][frag: ct0h,ct0l,ct1h,ct1l]

#pragma unroll
    for (int cq = 0; cq < 4; cq++) {            // preload tap 0 B's
        const int bo = 0 * LROWB + 0 * (DW * MSTR) + cq * 32;
        Bbuf[0][0][cq] = *(const v8h*)(lds + baseB[0] + bo);
        Bbuf[0][1][cq] = *(const v8h*)(lds + baseB[1] + bo);
    }
    {                                           // preload A(0,0)
        const uint4* wq = wp;
        Abuf[0][0] = *(const v8h*)(wq);
        Abuf[0][1] = *(const v8h*)(wq + 64);
        Abuf[0][2] = *(const v8h*)(wq + 128);
        Abuf[0][3] = *(const v8h*)(wq + 192);
    }

#pragma unroll
    for (int tap = 0; tap < 12; tap++) {
        const int tb = tap & 1, tn = tb ^ 1;
        if (tap < 11) {                         // prefetch next tap's 8 B-frags
            const int nt = tap + 1;
            const int kh = nt / 3, kw = nt % 3;
            const int bo = kh * LROWB + kw * (DW * MSTR);
#pragma unroll
            for (int cq = 0; cq < 4; cq++) {
                Bbuf[tn][0][cq] = *(const v8h*)(lds + baseB[0] + bo + cq * 32);
                Bbuf[tn][1][cq] = *(const v8h*)(lds + baseB[1] + bo + cq * 32);
            }
        }
#pragma unroll
        for (int cq = 0; cq < 4; cq++) {
            const int kk = tap * 4 + cq;
            const int ab = kk & 1, an = ab ^ 1;
            if (kk < 47) {                      // prefetch next A-fragment set
                const uint4* wq = wp + (size_t)(kk + 1) * 256;
                Abuf[an][0] = *(const v8h*)(wq);
                Abuf[an][1] = *(const v8h*)(wq + 64);
                Abuf[an][2] = *(const v8h*)(wq + 128);
                Abuf[an][3] = *(const v8h*)(wq + 192);
            }
            v8h A00 = Abuf[ab][0], A01 = Abuf[ab][1];
            v8h A10 = Abuf[ab][2], A11 = Abuf[ab][3];
            v8h B0 = Bbuf[tb][0][cq], B1 = Bbuf[tb][1][cq];
            acc[0][0][0] = __builtin_amdgcn_mfma_f32_32x32x16_f16(A00, B0, acc[0][0][0], 0, 0, 0);
            acc[0][0][1] = __builtin_amdgcn_mfma_f32_32x32x16_f16(A01, B0, acc[0][0][1], 0, 0, 0);
            acc[0][1][0] = __builtin_amdgcn_mfma_f32_32x32x16_f16(A10, B0, acc[0][1][0], 0, 0, 0);
            acc[0][1][1] = __builtin_amdgcn_mfma_f32_32x32x16_f16(A11, B0, acc[0][1][1], 0, 0, 0);
            acc[1][0][0] = __builtin_amdgcn_mfma_f32_32x32x16_f16(A00, B1, acc[1][0][0], 0, 0, 0);
            acc[1][0][1] = __builtin_amdgcn_mfma_f32_32x32x16_f16(A01, B1, acc[1][0][1], 0, 0, 0);
            acc[1][1][0] = __builtin_amdgcn_mfma_f32_32x32x16_f16(A10, B1, acc[1][1][0], 0, 0, 0);
            acc[1][1][1] = __builtin_amdgcn_mfma_f32_32x32x16_f16(A11, B1, acc[1][1][1], 0, 0, 0);
        }
    }

    // ---- epilogue: u = hi + lo/2048 ----
    const float invs = 1.0f / 2048.0f;
#pragma unroll
    for (int pt = 0; pt < 2; pt++) {
        if (tvalid[pt] && mm[pt] < NM && tt[pt] < NT) {
            float* base = u + ((size_t)(b * NT + tt[pt]) * NM + mm[pt]) * 64;
#pragma unroll
            for (int ct = 0; ct < 2; ct++) {
#pragma unroll
                for (int g = 0; g < 4; g++) {
                    int co = ct * 32 + 8 * g + 4 * hseg;
                    float4 val;
                    val.x = acc[pt][ct][0][4 * g + 0] + acc[pt][ct][1][4 * g + 0] * invs;
                    val.y = acc[pt][ct][0][4 * g + 1] + acc[pt][ct][1][4 * g + 1] * invs;
                    val.z = acc[pt][ct][0][4 * g + 2] + acc[pt][ct][1][4 * g + 2] * invs;
                    val.w = acc[pt][ct][0][4 * g + 3] + acc[pt][ct][1][4 * g + 3] * invs;
                    *(float4*)(base + co) = val;
                }
            }
        }
    }
}

// ---- LIF over T: u fp32 -> compact f16 spikes, unroll-8 ----
__global__ void lif_spikes(const float* __restrict__ u, half_t* __restrict__ s2) {
    int tid = blockIdx.x * 256 + threadIdx.x;   // 81920
    int b = tid / 2560;
    int cm = tid % 2560;
    const float* up = u + (size_t)b * NT * 2560 + cm;
    half_t* sp = s2 + (size_t)b * NT * 2560 + cm;
    float v = 0.f;
    const float TAUc = 10.0f / 7.0f;
    for (int tb = 0; tb < 128; tb += 8) {
        float uu[8];
#pragma unroll
        for (int k = 0; k < 8; k++) uu[k] = up[(size_t)(tb + k) * 2560];
#pragma unroll
        for (int k = 0; k < 8; k++) {
            v = v + (uu[k] - v) / TAUc;
            float s = (v >= 1.0f) ? 1.0f : 0.0f;
            sp[(size_t)(tb + k) * 2560] = (half_t)s;
            if (v >= 1.0f) v = 0.f;
        }
    }
    float uu = up[(size_t)128 * 2560];
    v = v + (uu - v) / TAUc;
    sp[(size_t)128 * 2560] = (half_t)((v >= 1.0f) ? 1.0f : 0.0f);
}

// ---- LIF3: spike counts only (mean commutes with FC), unroll-8 ----
__global__ void lif_sum(const float* __restrict__ u, float* __restrict__ hsum) {
    int tid = blockIdx.x * 256 + threadIdx.x;   // 81920
    int b = tid / 2560;
    int cm = tid % 2560;                         // = m*64 + co
    int m = cm >> 6;
    int co = cm & 63;
    const float* up = u + (size_t)b * NT * 2560 + cm;
    float v = 0.f, cnt = 0.f;
    const float TAUc = 10.0f / 7.0f;
    for (int tb = 0; tb < 128; tb += 8) {
        float uu[8];
#pragma unroll
        for (int k = 0; k < 8; k++) uu[k] = up[(size_t)(tb + k) * 2560];
#pragma unroll
        for (int k = 0; k < 8; k++) {
            v = v + (uu[k] - v) / TAUc;
            if (v >= 1.0f) { cnt += 1.0f; v = 0.f; }
        }
    }
    float uu = up[(size_t)128 * 2560];
    v = v + (uu - v) / TAUc;
    if (v >= 1.0f) cnt += 1.0f;
    hsum[b * 2560 + co * NM + m] = cnt;          // feature index = c*40 + m
}

// ---- FC on counts: y[b,k] = bf[k] + (sum_cm cnt*wf[k,cm]) / 129 ----
__global__ void fc_out(const float* __restrict__ hsum, const float* __restrict__ wf,
                       const float* __restrict__ bfv, float* __restrict__ out) {
    int b = blockIdx.x;
    int tid = threadIdx.x;
    float p[12];
#pragma unroll
    for (int k = 0; k < 12; k++) p[k] = 0.0f;
    for (int cm = tid; cm < NC * NM; cm += 256) {
        float h = hsum[b * NC * NM + cm];
#pragma unroll
        for (int k = 0; k < 12; k++) p[k] += h * wf[k * (NC * NM) + cm];
    }
    __shared__ float red[12][4];
    int lane = tid & 63, w = tid >> 6;
#pragma unroll
    for (int k = 0; k < 12; k++) {
        float s = p[k];
#pragma unroll
        for (int off = 32; off > 0; off >>= 1) s += __shfl_down(s, off, 64);
        if (lane == 0) red[k][w] = s;
    }
    __syncthreads();
    if (tid < 12) {
        float s = red[tid][0] + red[tid][1] + red[tid][2] + red[tid][3];
        out[b * 12 + tid] = bfv[tid] + s / 129.0f;
    }
}

extern "C" void kernel_launch(void* const* d_in, const int* in_sizes, int n_in,
                              void* d_out, int out_size, void* d_ws, size_t ws_size,
                              hipStream_t stream) {
    const float* x  = (const float*)d_in[0];
    const float* w1 = (const float*)d_in[1];
    const float* w2 = (const float*)d_in[2];
    const float* w3 = (const float*)d_in[3];
    const float* wf = (const float*)d_in[4];
    const float* bf = (const float*)d_in[5];
    float* out = (float*)d_out;

    char* ws = (char*)d_ws;
    half_t* s1  = (half_t*)ws;                      // 21,135,360 B
    half_t* s2  = (half_t*)(ws + 21135360);         // 21,135,360 B
    float*  u   = (float*)(ws + 42270720);          // 42,270,720 B
    uint4*  wf2 = (uint4*)(ws + 84541440);          // 786,432 B (4 copies)
    uint4*  wf3 = (uint4*)(ws + 85327872);          // 786,432 B (4 copies)
    float* hsum = (float*)(ws + 86114304);          // 327,680 B (end ~86.5 MB)

    prep_wfrag<<<48, 256, 0, stream>>>(w2, wf2);
    prep_wfrag<<<48, 256, 0, stream>>>(w3, wf3);

    conv1_lif1<<<dim3(10, 32), 256, 0, stream>>>(x, w1, s1);

    // layer 2: DH=4 PH=6 DW=3 PW=3, EXT=46: LDS = 7*46*136 = 43792 B (<64K)
    convP<4, 6, 3, 3, 46, 2><<<dim3(33, 32), 256, 43792, stream>>>(s1, wf2, u);
    lif_spikes<<<320, 256, 0, stream>>>(u, s2);

    // layer 3: DH=16 PH=24 DW=9 PW=9, EXT=58: LDS = 7*58*136 = 55216 B (<64K)
    convP<16, 24, 9, 9, 58, 4><<<dim3(33, 32), 256, 55216, stream>>>(s2, wf3, u);
    lif_sum<<<320, 256, 0, stream>>>(u, hsum);

    fc_out<<<32, 256, 0, stream>>>(hsum, wf, bf, out);
}